// Round 16
// baseline (27.322 us; speedup 1.0000x reference)
//
#include <hip/hip_runtime.h>
#include <math.h>

#define B_N 2048
#define DIM 32
#define K_N 10
#define NP  528          // sorted pairs (i<=j)
#define NCOLP 640        // padded column count (5 tiles x 128)
#define TILE 128
#define NT 5
#define NBLK (NT*NT*K_N)   // 250 blocks
#define CH 64              // samples per chunk
#define SMAX 448           // max cluster rows resident in LDS (Binomial +17.9 sigma)
#define SST  452           // sdT col stride (floats): mult of 4, 452%32=4 spreads banks

typedef __attribute__((ext_vector_type(8))) short bf16x8;   // 8 bf16 = 4 VGPRs
typedef __attribute__((ext_vector_type(4))) float f32x4;    // mfma 16x16 accum

__device__ __forceinline__ float c2f(float x) {
  float r = sqrtf(fabsf(x) + 0.25f) - 0.5f;
  return (x >= 0.f) ? r : -r;
}
__device__ __forceinline__ float c3f(float x) {
  float v = fabsf(x) + 0.19245008973f;
  float r = exp2f(log2f(v) * 0.33333333333f) - 0.57735026919f;
  return (x >= 0.f) ? r : -r;
}
__device__ __forceinline__ float c4f(float x) {
  float r = sqrtf(sqrtf(fabsf(x) + 0.15749013123f)) - 0.62996052494f;
  return (x >= 0.f) ? r : -r;
}
#define T4C1 (sqrtf(sqrtf(1.f + 0.15749013123f)) - 0.62996052494f)

// col -> (u,v) with d[32]=1 (ones), d[33]=0 (pad)
__device__ __forceinline__ void decode_col(int g, int& u, int& v) {
  if (g < NP) {
    int j = (int)((sqrtf(8.f * (float)g + 1.f) - 1.f) * 0.5f);
    while (j * (j + 1) / 2 > g) --j;
    while ((j + 1) * (j + 2) / 2 <= g) ++j;
    u = g - j * (j + 1) / 2; v = j;
  } else if (g < 560) { u = g - NP; v = 32; }
  else if (g == 560)  { u = 32; v = 32; }
  else                { u = 33; v = 33; }
}

// fp32 -> bf16 bits, round-to-nearest-even
__device__ __forceinline__ unsigned short f2bf(float f) {
  unsigned u = __builtin_bit_cast(unsigned, f);
  return (unsigned short)((u + 0x7FFFu + ((u >> 16) & 1u)) >> 16);
}

// ---- single compute kernel: argmax + scatter-direct + expand + MFMA + fused loss ----
__global__ __launch_bounds__(1024) void k_main(const float* __restrict__ emb,
                                               const float* __restrict__ cen,
                                               const float* __restrict__ lg,
                                               float* __restrict__ out) {
  const int k  = blockIdx.z;
  const int Pt = blockIdx.y, Qt = blockIdx.x;
  const int t  = threadIdx.x;
  const int wid = t >> 6, lane = t & 63;
  const int wr = wid >> 2, wc = wid & 3;          // 4x4 wave grid over 128x128 tile
  const int lr = lane & 15, kg = lane >> 4;

  __shared__ unsigned char tI0[NCOLP], tI1[NCOLP];
  __shared__ __align__(16) float sdT[34][SST];    // dim-major, whole cluster resident
  __shared__ __align__(16) unsigned short tiles[2][2][8][TILE][8]; // [buf][side][ch][col][8]
  __shared__ float scen[DIM];
  __shared__ int wcs[32];
  __shared__ float sred[16];

  // ---- prologue: tables + both argmax rounds before any barrier ----
  if (t < NCOLP) {
    int u, v; decode_col(t, u, v);
    tI0[t] = (unsigned char)u; tI1[t] = (unsigned char)v;
  }
  if (t < DIM) scen[t] = cen[k * DIM + t];

  const int e0 = t, e1 = 1024 + t;
  const float2* l0 = reinterpret_cast<const float2*>(lg + (size_t)e0 * K_N);
  const float2* l1 = reinterpret_cast<const float2*>(lg + (size_t)e1 * K_N);
  float b0, b1; int i0 = 0, i1 = 0;
  {
    float2 p0 = l0[0], p1 = l1[0];
    b0 = p0.x; if (p0.y > b0) { b0 = p0.y; i0 = 1; }
    b1 = p1.x; if (p1.y > b1) { b1 = p1.y; i1 = 1; }
    #pragma unroll
    for (int q = 1; q < 5; ++q) {
      float2 q0 = l0[q], q1 = l1[q];
      if (q0.x > b0) { b0 = q0.x; i0 = q * 2; }
      if (q0.y > b0) { b0 = q0.y; i0 = q * 2 + 1; }
      if (q1.x > b1) { b1 = q1.x; i1 = q * 2; }
      if (q1.y > b1) { b1 = q1.y; i1 = q * 2 + 1; }
    }
  }
  const bool f0 = (i0 == k), f1 = (i1 == k);
  unsigned long long m0 = __ballot(f0);
  unsigned long long m1 = __ballot(f1);
  int pre0 = __popcll(m0 & ((1ull << lane) - 1ull));
  int pre1 = __popcll(m1 & ((1ull << lane) - 1ull));
  if (lane == 0) { wcs[wid] = __popcll(m0); wcs[16 + wid] = __popcll(m1); }
  __syncthreads();                                         // barrier A
  int off0 = 0, total0 = 0, off1 = 0, nb = 0;
  #pragma unroll
  for (int q = 0; q < 16; ++q) {
    int c0 = wcs[q], c1 = wcs[16 + q];
    if (q < wid) { off0 += c0; off1 += c1; }
    total0 += c0; nb += c1;
  }
  off1 += total0; nb += total0;
  if (nb > SMAX) nb = SMAX;                                // unreachable (+17.9 sigma)
  const int nbp = (nb + CH - 1) & ~(CH - 1);

  // ---- scatter-direct: selected threads write their diff row (transposed) ----
  const float4* e4 = reinterpret_cast<const float4*>(emb);
  if (f0) {
    int p = off0 + pre0;
    if (p < SMAX) {
      #pragma unroll
      for (int q = 0; q < 8; ++q) {
        float4 e = e4[e0 * 8 + q];
        sdT[q * 4 + 0][p] = e.x - scen[q * 4 + 0];
        sdT[q * 4 + 1][p] = e.y - scen[q * 4 + 1];
        sdT[q * 4 + 2][p] = e.z - scen[q * 4 + 2];
        sdT[q * 4 + 3][p] = e.w - scen[q * 4 + 3];
      }
    }
  }
  if (f1) {
    int p = off1 + pre1;
    if (p < SMAX) {
      #pragma unroll
      for (int q = 0; q < 8; ++q) {
        float4 e = e4[e1 * 8 + q];
        sdT[q * 4 + 0][p] = e.x - scen[q * 4 + 0];
        sdT[q * 4 + 1][p] = e.y - scen[q * 4 + 1];
        sdT[q * 4 + 2][p] = e.z - scen[q * 4 + 2];
        sdT[q * 4 + 3][p] = e.w - scen[q * 4 + 3];
      }
    }
  }
  // ones row, pad dim, and zero-fill of pad sample columns
  if (t < SMAX) { sdT[32][t] = (t < nb) ? 1.f : 0.f; sdT[33][t] = 0.f; }
  for (int s = nb + t; s < nbp; s += 1024) {
    #pragma unroll
    for (int d = 0; d < DIM; ++d) sdT[d][s] = 0.f;
  }
  __syncthreads();                                         // barrier B: sdT ready

  f32x4 acc[2][2];
  {
    f32x4 z = {0.f, 0.f, 0.f, 0.f};
    acc[0][0] = z; acc[0][1] = z; acc[1][0] = z; acc[1][1] = z;
  }

  int pp = 0;
  for (int cb = 0; cb < nbp; cb += CH, pp ^= 1) {
    // expand: 2 bf16x8 units per thread; vector b128 reads from resident sdT
    #pragma unroll
    for (int uu = 0; uu < 2; ++uu) {
      int unit = t + uu * 1024;
      int side = unit >> 10;
      int rem  = unit & 1023;
      int ch = rem >> 7, col = rem & 127;
      int gcol = (side ? Qt : Pt) * TILE + col;
      int u = tI0[gcol], v = tI1[gcol];
      const float4* pu = reinterpret_cast<const float4*>(&sdT[u][cb + ch * 8]);
      const float4* pv = reinterpret_cast<const float4*>(&sdT[v][cb + ch * 8]);
      float4 u0 = pu[0], u1 = pu[1], v0 = pv[0], v1 = pv[1];
      bf16x8 pk;
      pk[0] = (short)f2bf(u0.x * v0.x); pk[1] = (short)f2bf(u0.y * v0.y);
      pk[2] = (short)f2bf(u0.z * v0.z); pk[3] = (short)f2bf(u0.w * v0.w);
      pk[4] = (short)f2bf(u1.x * v1.x); pk[5] = (short)f2bf(u1.y * v1.y);
      pk[6] = (short)f2bf(u1.z * v1.z); pk[7] = (short)f2bf(u1.w * v1.w);
      *reinterpret_cast<bf16x8*>(&tiles[pp][side][ch][col][0]) = pk;
    }
    __syncthreads();                                       // tiles[pp] ready
    // 2 K-steps x 4 MFMA per wave (fragment addressing family validated r8-r15);
    // next iteration writes tiles[pp^1]; its barrier orders reuse of tiles[pp]
    #pragma unroll
    for (int s = 0; s < 2; ++s) {
      bf16x8 a[2], b[2];
      #pragma unroll
      for (int f = 0; f < 2; ++f) {
        a[f] = *reinterpret_cast<const bf16x8*>(&tiles[pp][0][s * 4 + kg][wr * 32 + f * 16 + lr][0]);
        b[f] = *reinterpret_cast<const bf16x8*>(&tiles[pp][1][s * 4 + kg][wc * 32 + f * 16 + lr][0]);
      }
      #pragma unroll
      for (int fa = 0; fa < 2; ++fa)
        #pragma unroll
        for (int fc = 0; fc < 2; ++fc)
          acc[fa][fc] = __builtin_amdgcn_mfma_f32_16x16x32_bf16(a[fa], b[fc], acc[fa][fc], 0, 0, 0);
    }
  }

  // ---- fused epilogue (same algebra; validated absmax=0 r2/r5/r6/r8/r10-r15) ----
  // C/D layout (m89-verified): Q(col) = lane&15, P(row) = (lane>>4)*4 + reg
  const int pb = Pt * TILE + wr * 32;
  const int qb = Qt * TILE + wc * 32;
  const float inv_cnt = 1.f / ((float)nb + 1e-7f);
  float sum = 0.f;
  #pragma unroll
  for (int fa = 0; fa < 2; ++fa) {
    #pragma unroll
    for (int r = 0; r < 4; ++r) {
      const int P = pb + fa * 16 + kg * 4 + r;
      const int i = tI0[P], j = tI1[P];
      #pragma unroll
      for (int fc = 0; fc < 2; ++fc) {
        const int Q = qb + fc * 16 + lr;
        const int li = tI0[Q], mi = tI1[Q];
        const float g = acc[fa][fc][r];
        if (P < NP) {
          if (Q < NP) {
            int s0 = min(i, li), x1 = max(i, li), x2 = min(j, mi), s3 = max(j, mi);
            int s1 = min(x1, x2), s2 = max(x1, x2);
            bool e01 = (s0 == s1), e12 = (s1 == s2), e23 = (s2 == s3);
            float wgt, tgt = 0.f;
            if (e01 && e12 && e23)                 wgt = 0.f;
            else if (e01 && e23)                   { wgt = 2.f / 9.f; tgt = T4C1; }
            else if ((e01 && e12) || (e12 && e23)) wgt = 0.25f;
            else if (e01 || e12 || e23)            wgt = 5.f / 24.f;
            else                                   wgt = 1.f / 6.f;
            float d = c4f(g) - tgt;
            sum += 0.125f * wgt * d * d;
          } else if (Q < 560) {
            if (Q - NP >= j) { float d = c3f(g); sum += 0.25f * d * d; }
          } else if (Q == 560) {
            if (i < j) { float d = c2f(g * inv_cnt); sum += 0.5f * d * d; }
          }
        } else if (P < 560 && Q == 560) {
          float m1 = g * inv_cnt;
          sum += m1 * m1;
        }
      }
    }
  }

  #pragma unroll
  for (int off = 32; off > 0; off >>= 1) sum += __shfl_down(sum, off, 64);
  if (lane == 0) sred[wid] = sum;
  __syncthreads();
  if (t == 0) {
    float s = 0.f;
    #pragma unroll
    for (int q = 0; q < 16; ++q) s += sred[q];
    atomicAdd(out, s * ((float)nb * (1.f / (float)B_N)));   // direct device-scope accumulate
  }
}

extern "C" void kernel_launch(void* const* d_in, const int* in_sizes, int n_in,
                              void* d_out, int out_size, void* d_ws, size_t ws_size,
                              hipStream_t stream) {
  const float* emb = (const float*)d_in[0];
  const float* cen = (const float*)d_in[1];
  const float* lg  = (const float*)d_in[2];
  float* out = (float*)d_out;

  (void)hipMemsetAsync(d_out, 0, (size_t)out_size * 4, stream);  // zero the accumulator
  k_main<<<dim3(NT, NT, K_N), 1024, 0, stream>>>(emb, cen, lg, out);
}

// Round 17
// 26.027 us; speedup vs baseline: 1.0497x; 1.0497x over previous
//
#include <hip/hip_runtime.h>
#include <math.h>

#define B_N 2048
#define DIM 32
#define K_N 10
#define NP  528          // sorted pairs (i<=j)
#define NCOLP 640        // padded column count (5 tiles x 128)
#define TILE 128
#define NT 5
#define NBLK (NT*NT*K_N)   // 250 blocks
#define CH 64              // samples per chunk
#define SDST 68            // sdT row stride (floats)

typedef __attribute__((ext_vector_type(8))) short bf16x8;   // 8 bf16 = 4 VGPRs
typedef __attribute__((ext_vector_type(4))) float f32x4;    // mfma 16x16 accum

__device__ __forceinline__ float c2f(float x) {
  float r = sqrtf(fabsf(x) + 0.25f) - 0.5f;
  return (x >= 0.f) ? r : -r;
}
__device__ __forceinline__ float c3f(float x) {
  float v = fabsf(x) + 0.19245008973f;
  float r = exp2f(log2f(v) * 0.33333333333f) - 0.57735026919f;
  return (x >= 0.f) ? r : -r;
}
__device__ __forceinline__ float c4f(float x) {
  float r = sqrtf(sqrtf(fabsf(x) + 0.15749013123f)) - 0.62996052494f;
  return (x >= 0.f) ? r : -r;
}
#define T4C1 (sqrtf(sqrtf(1.f + 0.15749013123f)) - 0.62996052494f)

// col -> (u,v) with d[32]=1 (ones), d[33]=0 (pad)
__device__ __forceinline__ void decode_col(int g, int& u, int& v) {
  if (g < NP) {
    int j = (int)((sqrtf(8.f * (float)g + 1.f) - 1.f) * 0.5f);
    while (j * (j + 1) / 2 > g) --j;
    while ((j + 1) * (j + 2) / 2 <= g) ++j;
    u = g - j * (j + 1) / 2; v = j;
  } else if (g < 560) { u = g - NP; v = 32; }
  else if (g == 560)  { u = 32; v = 32; }
  else                { u = 33; v = 33; }
}

// fp32 -> bf16 bits, round-to-nearest-even
__device__ __forceinline__ unsigned short f2bf(float f) {
  unsigned u = __builtin_bit_cast(unsigned, f);
  return (unsigned short)((u + 0x7FFFu + ((u >> 16) & 1u)) >> 16);
}

// ---- single compute kernel: argmax + compact + expand + MFMA Gram + fused loss ----
__global__ __launch_bounds__(1024) void k_main(const float* __restrict__ emb,
                                               const float* __restrict__ cen,
                                               const float* __restrict__ lg,
                                               float* __restrict__ out) {
  const int k  = blockIdx.z;
  const int Pt = blockIdx.y, Qt = blockIdx.x;
  const int t  = threadIdx.x;
  const int wid = t >> 6, lane = t & 63;
  const int wr = wid >> 2, wc = wid & 3;          // 4x4 wave grid over 128x128 tile
  const int lr = lane & 15, kg = lane >> 4;

  __shared__ unsigned char tI0[NCOLP], tI1[NCOLP];
  __shared__ unsigned short rl[B_N];                       // cluster row list
  __shared__ __align__(16) float sdT[34][SDST];            // dim-major diff (+ones,+zero)
  __shared__ __align__(16) unsigned short tiles[2][2][8][TILE][8]; // [buf][side][ch][col][8]
  __shared__ float scen[DIM];
  __shared__ int wcs[32];
  __shared__ float sred[16];

  // ---- prologue: tables + both argmax rounds (float2-vectorized) before any barrier ----
  if (t < NCOLP) {
    int u, v; decode_col(t, u, v);
    tI0[t] = (unsigned char)u; tI1[t] = (unsigned char)v;
  }
  if (t < DIM) scen[t] = cen[k * DIM + t];

  const int e0 = t, e1 = 1024 + t;
  const float2* l0 = reinterpret_cast<const float2*>(lg + (size_t)e0 * K_N);
  const float2* l1 = reinterpret_cast<const float2*>(lg + (size_t)e1 * K_N);
  float b0, b1; int i0 = 0, i1 = 0;
  {
    float2 p0 = l0[0], p1 = l1[0];
    b0 = p0.x; if (p0.y > b0) { b0 = p0.y; i0 = 1; }
    b1 = p1.x; if (p1.y > b1) { b1 = p1.y; i1 = 1; }
    #pragma unroll
    for (int q = 1; q < 5; ++q) {
      float2 q0 = l0[q], q1 = l1[q];
      if (q0.x > b0) { b0 = q0.x; i0 = q * 2; }
      if (q0.y > b0) { b0 = q0.y; i0 = q * 2 + 1; }
      if (q1.x > b1) { b1 = q1.x; i1 = q * 2; }
      if (q1.y > b1) { b1 = q1.y; i1 = q * 2 + 1; }
    }
  }
  const bool f0 = (i0 == k), f1 = (i1 == k);
  unsigned long long m0 = __ballot(f0);
  unsigned long long m1 = __ballot(f1);
  int pre0 = __popcll(m0 & ((1ull << lane) - 1ull));
  int pre1 = __popcll(m1 & ((1ull << lane) - 1ull));
  if (lane == 0) { wcs[wid] = __popcll(m0); wcs[16 + wid] = __popcll(m1); }
  __syncthreads();                                         // barrier A
  int off0 = 0, total0 = 0, off1 = 0, nb = 0;
  #pragma unroll
  for (int q = 0; q < 16; ++q) {
    int c0 = wcs[q], c1 = wcs[16 + q];
    if (q < wid) { off0 += c0; off1 += c1; }
    total0 += c0; nb += c1;
  }
  off1 += total0; nb += total0;
  if (f0) rl[off0 + pre0] = (unsigned short)e0;
  if (f1) rl[off1 + pre1] = (unsigned short)e1;
  __syncthreads();                                         // barrier B: rl ready

  f32x4 acc[2][2];
  {
    f32x4 z = {0.f, 0.f, 0.f, 0.f};
    acc[0][0] = z; acc[0][1] = z; acc[1][0] = z; acc[1][1] = z;
  }

  const float4* e4 = reinterpret_cast<const float4*>(emb);
  const int gr = t >> 3, gpart = t & 7;           // gather role (t < 512)

  // prefetch chunk 0
  float4 pf = make_float4(0.f, 0.f, 0.f, 0.f);
  bool pvalid = false;
  if (t < 512) {
    pvalid = (gr < nb);
    if (pvalid) {
      float4 e = e4[rl[gr] * 8 + gpart];
      pf = make_float4(e.x - scen[gpart * 4], e.y - scen[gpart * 4 + 1],
                       e.z - scen[gpart * 4 + 2], e.w - scen[gpart * 4 + 3]);
    }
  }

  int pp = 0;
  for (int cb = 0; cb < nb; cb += CH, pp ^= 1) {
    // write prefetched diff rows to transposed LDS
    if (t < 512) {
      sdT[gpart * 4 + 0][gr] = pf.x;
      sdT[gpart * 4 + 1][gr] = pf.y;
      sdT[gpart * 4 + 2][gr] = pf.z;
      sdT[gpart * 4 + 3][gr] = pf.w;
      if (gpart == 0) { sdT[32][gr] = pvalid ? 1.f : 0.f; sdT[33][gr] = 0.f; }
    }
    __syncthreads();
    // issue next chunk's gather (latency hides under expand + MFMA)
    if (t < 512) {
      int idx = cb + CH + gr;
      pvalid = (idx < nb);
      pf = make_float4(0.f, 0.f, 0.f, 0.f);
      if (pvalid) {
        float4 e = e4[rl[idx] * 8 + gpart];
        pf = make_float4(e.x - scen[gpart * 4], e.y - scen[gpart * 4 + 1],
                         e.z - scen[gpart * 4 + 2], e.w - scen[gpart * 4 + 3]);
      }
    }
    // expand: 2 bf16x8 units per thread; vector b128 LDS reads from sdT
    #pragma unroll
    for (int uu = 0; uu < 2; ++uu) {
      int unit = t + uu * 1024;
      int side = unit >> 10;
      int rem  = unit & 1023;
      int ch = rem >> 7, col = rem & 127;
      int gcol = (side ? Qt : Pt) * TILE + col;
      int u = tI0[gcol], v = tI1[gcol];
      const float4* pu = reinterpret_cast<const float4*>(&sdT[u][ch * 8]);
      const float4* pv = reinterpret_cast<const float4*>(&sdT[v][ch * 8]);
      float4 u0 = pu[0], u1 = pu[1], v0 = pv[0], v1 = pv[1];
      bf16x8 pk;
      pk[0] = (short)f2bf(u0.x * v0.x); pk[1] = (short)f2bf(u0.y * v0.y);
      pk[2] = (short)f2bf(u0.z * v0.z); pk[3] = (short)f2bf(u0.w * v0.w);
      pk[4] = (short)f2bf(u1.x * v1.x); pk[5] = (short)f2bf(u1.y * v1.y);
      pk[6] = (short)f2bf(u1.z * v1.z); pk[7] = (short)f2bf(u1.w * v1.w);
      *reinterpret_cast<bf16x8*>(&tiles[pp][side][ch][col][0]) = pk;
    }
    __syncthreads();
    // 2 K-steps x 4 MFMA per wave (fragment addressing family validated r8-r16)
    #pragma unroll
    for (int s = 0; s < 2; ++s) {
      bf16x8 a[2], b[2];
      #pragma unroll
      for (int f = 0; f < 2; ++f) {
        a[f] = *reinterpret_cast<const bf16x8*>(&tiles[pp][0][s * 4 + kg][wr * 32 + f * 16 + lr][0]);
        b[f] = *reinterpret_cast<const bf16x8*>(&tiles[pp][1][s * 4 + kg][wc * 32 + f * 16 + lr][0]);
      }
      #pragma unroll
      for (int fa = 0; fa < 2; ++fa)
        #pragma unroll
        for (int fc = 0; fc < 2; ++fc)
          acc[fa][fc] = __builtin_amdgcn_mfma_f32_16x16x32_bf16(a[fa], b[fc], acc[fa][fc], 0, 0, 0);
    }
  }
  __syncthreads();

  // ---- fused epilogue (same algebra; validated absmax=0 r2/r5/r6/r8/r10-r16) ----
  // C/D layout (m89-verified): Q(col) = lane&15, P(row) = (lane>>4)*4 + reg
  const int pb = Pt * TILE + wr * 32;
  const int qb = Qt * TILE + wc * 32;
  const float inv_cnt = 1.f / ((float)nb + 1e-7f);
  float sum = 0.f;
  #pragma unroll
  for (int fa = 0; fa < 2; ++fa) {
    #pragma unroll
    for (int r = 0; r < 4; ++r) {
      const int P = pb + fa * 16 + kg * 4 + r;
      const int i = tI0[P], j = tI1[P];
      #pragma unroll
      for (int fc = 0; fc < 2; ++fc) {
        const int Q = qb + fc * 16 + lr;
        const int li = tI0[Q], mi = tI1[Q];
        const float g = acc[fa][fc][r];
        if (P < NP) {
          if (Q < NP) {
            int s0 = min(i, li), x1 = max(i, li), x2 = min(j, mi), s3 = max(j, mi);
            int s1 = min(x1, x2), s2 = max(x1, x2);
            bool e01 = (s0 == s1), e12 = (s1 == s2), e23 = (s2 == s3);
            float wgt, tgt = 0.f;
            if (e01 && e12 && e23)                 wgt = 0.f;
            else if (e01 && e23)                   { wgt = 2.f / 9.f; tgt = T4C1; }
            else if ((e01 && e12) || (e12 && e23)) wgt = 0.25f;
            else if (e01 || e12 || e23)            wgt = 5.f / 24.f;
            else                                   wgt = 1.f / 6.f;
            float d = c4f(g) - tgt;
            sum += 0.125f * wgt * d * d;
          } else if (Q < 560) {
            if (Q - NP >= j) { float d = c3f(g); sum += 0.25f * d * d; }
          } else if (Q == 560) {
            if (i < j) { float d = c2f(g * inv_cnt); sum += 0.5f * d * d; }
          }
        } else if (P < 560 && Q == 560) {
          float m1 = g * inv_cnt;
          sum += m1 * m1;
        }
      }
    }
  }

  #pragma unroll
  for (int off = 32; off > 0; off >>= 1) sum += __shfl_down(sum, off, 64);
  if (lane == 0) sred[wid] = sum;
  __syncthreads();
  if (t == 0) {
    float s = 0.f;
    #pragma unroll
    for (int q = 0; q < 16; ++q) s += sred[q];
    atomicAdd(out, s * ((float)nb * (1.f / (float)B_N)));   // direct device-scope accumulate
  }
}

extern "C" void kernel_launch(void* const* d_in, const int* in_sizes, int n_in,
                              void* d_out, int out_size, void* d_ws, size_t ws_size,
                              hipStream_t stream) {
  const float* emb = (const float*)d_in[0];
  const float* cen = (const float*)d_in[1];
  const float* lg  = (const float*)d_in[2];
  float* out = (float*)d_out;

  (void)hipMemsetAsync(d_out, 0, (size_t)out_size * 4, stream);  // zero the accumulator
  k_main<<<dim3(NT, NT, K_N), 1024, 0, stream>>>(emb, cen, lg, out);
}